// Round 11
// baseline (210.151 us; speedup 1.0000x reference)
//
#include <hip/hip_runtime.h>

// 3x3 conv (sparse weights treated dense), NCHW/OIHW, stride1 pad1, fp32 I/O.
// B=32, CIN=COUT=256, H=W=56.
//
// R11: zero-LDS-dependency MFMA clusters + swizzled exact-64B LDS layout.
//  - wave = 64c x 112p m4n7 (best B/FLOP), block 256 thr / 4 waves.
//  - Within a cb all 9 taps read the same X buffer -> B-frags for tap t+1
//    ds_read DURING tap t (bv ping-pong regs). A 3-deep buffered -> stage
//    A(t+2) never aliases a buffer still being read -> 1 barrier/tap.
//  - LDS exact 64B/slot, chunk involution q = c ^ ((c>>3)&7) applied to
//    gload SOURCE (per-lane) and read offsets (both-sides, rule #21):
//    uniform 2-lanes/bank-group (free) instead of pad tricks.
//  - LDS = 3x16K (A) + 2x16K (X) = 80KB -> 2 blocks/CU. vmcnt counted
//    (4/8), never 0 mid-loop. Loop = 4 x 18-tap unrolled (static parity).

typedef __attribute__((ext_vector_type(8))) short short8;
typedef __attribute__((ext_vector_type(4))) float f32x4;
typedef __attribute__((ext_vector_type(4))) int i32x4;

constexpr int BB = 32, CIN = 256, COUT = 256, H = 56, W = 56, HW = H * W;
constexpr int HP = 58, WP = 58;

constexpr size_t XP_ELEMS = (size_t)BB * HP * WP * CIN;
constexpr size_t WB_ELEMS = (size_t)COUT * 9 * CIN;
constexpr size_t WS_NEEDED = (XP_ELEMS + WB_ELEMS) * 2;

__device__ __forceinline__ ushort f2bf(float f) {
    unsigned x = __float_as_uint(f);
    unsigned r = (x + 0x7FFFu + ((x >> 16) & 1u)) >> 16;   // RNE
    return (ushort)r;
}

// ---------------- prep kernels (unchanged) ----------------

__global__ __launch_bounds__(256)
void prep_xp(const float* __restrict__ x, ushort* __restrict__ xp) {
    const int bi = blockIdx.x;            // b*58 + padded row i
    const int b = bi / HP, i = bi % HP;
    ushort* dst = xp + (size_t)bi * WP * CIN;
    const int tid = threadIdx.x;

    if (i == 0 || i == HP - 1) {
        i32x4 z = {0, 0, 0, 0};
        for (int k = tid; k < WP * CIN / 8; k += 256) ((i32x4*)dst)[k] = z;
        return;
    }

    __shared__ ushort t[W][CIN + 2];
    const int lane = tid & 63, wv = tid >> 6;
    if (lane < W) {
        const float* src = x + (size_t)b * CIN * HW + (size_t)(i - 1) * W + lane;
        for (int cin = wv; cin < CIN; cin += 4)
            t[lane][cin] = f2bf(src[(size_t)cin * HW]);
    }
    __syncthreads();
    for (int c = 0; c < WP; ++c)
        dst[c * CIN + tid] = (c == 0 || c == WP - 1) ? (ushort)0 : t[c - 1][tid];
}

// wb2: [t = cb*9+tap][cout][ci], ci = cin%32. Slab = 8192 elems.
__global__ __launch_bounds__(256)
void prep_wb2(const float* __restrict__ w, ushort* __restrict__ wb2) {
    const int d = blockIdx.x * 256 + threadIdx.x;
    const int ci = d & 31;
    const int cout = (d >> 5) & 255;
    const int r = d >> 13;                // 0..71
    const int tap = r % 9, cb = r / 9;
    const int cin = cb * 32 + ci;
    wb2[d] = f2bf(w[((size_t)cout * CIN + cin) * 9 + tap]);
}

// ---------------- MFMA conv ----------------

#define SCHED_FENCE() __builtin_amdgcn_sched_barrier(0)
#define WAITV0 asm volatile("s_waitcnt vmcnt(0)" ::: "memory")
#define WAITV4 asm volatile("s_waitcnt vmcnt(4)" ::: "memory")
#define WAITV8 asm volatile("s_waitcnt vmcnt(8)" ::: "memory")

__device__ __forceinline__ void gload_lds16(const ushort* g, ushort* l) {
    __builtin_amdgcn_global_load_lds(
        (const __attribute__((address_space(1))) void*)g,
        (__attribute__((address_space(3))) void*)l, 16, 0, 0);
}

// chunk involution (16B units): flips bits 0-2 with bits 3-5 -> spreads
// row bits into bank-group bits. Self-inverse (bits>=3 unchanged).
__device__ __forceinline__ int swz(int c) { return c ^ ((c >> 3) & 7); }

__global__ __launch_bounds__(256, 2)
void conv_mfma(const ushort* __restrict__ xp, const ushort* __restrict__ wb2,
               float* __restrict__ out) {
    // XCD-aware swizzle: 896 blocks = 8 * 112
    int bx = blockIdx.x;
    bx = (bx & 7) * 112 + (bx >> 3);

    const int b  = bx / 28;
    const int p0 = (bx % 28) * 112;        // 112-pix strip = 2 output rows
    const int r0 = p0 / 56;                // first padded input row

    const int tid  = threadIdx.x;
    const int wv   = tid >> 6;             // 0..3, wave -> couts [64wv, 64wv+64)
    const int lane = tid & 63;
    const int ml   = lane & 15;
    const int g    = lane >> 4;

    __shared__ ushort As[3][8192];         // 3 x 16KB, chunk c = cout*4 + piece
    __shared__ ushort Xs[2][8192];         // 2 x 16KB, chunk c = slot*4 + piece
                                           // (slot = row*58+col, 232 slots -> c<928)

    // A-frag read offsets (bytes, swizzled): cout = 64wv+16mi+ml, piece g
    int aoffB[4];
    #pragma unroll
    for (int mi = 0; mi < 4; ++mi) {
        const int c = (64 * wv + 16 * mi + ml) * 4 + g;
        aoffB[mi] = swz(c) * 16;
    }
    // B-frag chunk bases: pixel p_ = p0 + 16nf + ml -> slot; piece g
    int cbase[7];
    #pragma unroll
    for (int nf = 0; nf < 7; ++nf) {
        const int p_  = p0 + 16 * nf + ml;
        const int hl  = (p_ >= p0 + 56) ? 1 : 0;
        const int col = p_ - 56 * (r0 + hl);
        cbase[nf] = ((hl * 58 + col) * 4 + g);
    }
    // staging source offsets: thread covers positions q = k*256+tid; data for
    // logical chunk c = swz(q) must land at q (inverse-swizzled source).
    int goffA[4], goffX[4];
    #pragma unroll
    for (int k = 0; k < 4; ++k) {
        const int q = k * 256 + tid;
        const int c = swz(q);
        goffA[k] = (c >> 2) * 32 + (c & 3) * 8;                  // elems in slab
        goffX[k] = (c < 928) ? ((c >> 2) * 256 + (c & 3) * 8) : 0;
    }
    const size_t xbase = ((size_t)b * HP + r0) * WP * CIN;

    f32x4 acc[4][7] = {};
    short8 bvv[2][7];

    #define STAGE_A(SLAB, BUF)                                                  \
        { const ushort* _s = wb2 + (size_t)(SLAB) * 8192;                       \
          _Pragma("unroll")                                                     \
          for (int k = 0; k < 4; ++k)                                           \
              gload_lds16(_s + goffA[k], &As[BUF][(k * 256 + wv * 64) * 8]); }
    #define STAGE_X(SLAB, BUF)                                                  \
        { const ushort* _s = xp + xbase + (SLAB) * 32;                          \
          _Pragma("unroll")                                                     \
          for (int k = 0; k < 4; ++k)                                           \
              gload_lds16(_s + goffX[k], &Xs[BUF][(k * 256 + wv * 64) * 8]); }

    // prologue: X(0)->Xs0, A(0)->As0, A(1)->As1; retire X(0)+A(0); preload bv(tap0)
    STAGE_X(0, 0);
    STAGE_A(0, 0);
    STAGE_A(1, 1);
    WAITV4;                                 // leaves A(1) in flight
    __syncthreads();
    #pragma unroll
    for (int nf = 0; nf < 7; ++nf)
        bvv[0][nf] = *(const short8*)((const char*)&Xs[0][0] + swz(cbase[nf]) * 16);

    const int DSLOT[9] = {0, 1, 2, 58, 59, 60, 116, 117, 118};

    for (int j = 0; j < 4; ++j) {          // cbs (2j, 2j+1)
        #pragma unroll
        for (int tt = 0; tt < 18; ++tt) {  // t = 18j + tt
            const int tap  = tt % 9;
            const int half = tt / 9;       // Xs[half] is current
            // tap8: retire the X staged at tap6 before reading it
            if (tap == 8) { WAITV4; SCHED_FENCE(); }

            // stage A(t+2) into As[(t+2)%3] (readers finished at t-1's barrier)
            int slab = 18 * j + tt + 2;
            if (slab >= 72) slab -= 72;    // t=70/71: garbage into never-read buf
            STAGE_A(slab, (tt + 2) % 3);
            if (tap == 6) {                // stage next cb's X (2-tap cover)
                int xsl = 2 * j + 1 + half;
                if (xsl >= 8) xsl = 0;     // cb7: garbage into unread Xs[0]
                STAGE_X(xsl, half ^ 1);
            }

            // av(t): landed (retired at t-1), read at top — only wait pre-MFMA
            const ushort* Ab = &As[tt % 3][0];
            short8 av[4];
            #pragma unroll
            for (int mi = 0; mi < 4; ++mi)
                av[mi] = *(const short8*)((const char*)Ab + aoffB[mi]);
            // bv prefetch for tap t+1 (Xs stable within cb; tap8 -> next buffer)
            const int ntap = (tap == 8) ? 0 : (tap + 1);
            const ushort* Xb = &Xs[(tap == 8) ? (half ^ 1) : half][0];
            #pragma unroll
            for (int nf = 0; nf < 7; ++nf) {
                const int c = cbase[nf] + 4 * DSLOT[ntap];
                bvv[(tt + 1) & 1][nf] =
                    *(const short8*)((const char*)Xb + swz(c) * 16);
            }

            __builtin_amdgcn_s_setprio(1);
            #pragma unroll
            for (int mi = 0; mi < 4; ++mi)
                #pragma unroll
                for (int nf = 0; nf < 7; ++nf)
                    acc[mi][nf] = __builtin_amdgcn_mfma_f32_16x16x32_bf16(
                                      av[mi], bvv[tt & 1][nf], acc[mi][nf], 0, 0, 0);
            __builtin_amdgcn_s_setprio(0);
            SCHED_FENCE();
            // retire oldest A stage (keep A(t+2) [+X] in flight — never drain)
            if (tap == 6 || tap == 7) { WAITV8; } else { WAITV4; }
            SCHED_FENCE();
            __builtin_amdgcn_s_barrier();
            SCHED_FENCE();
        }
    }
    WAITV0;                                // drain tail garbage stages

    // epilogue: D[row=4g+r][col=ml] (verified R2-R10)
    float* ob = out + (size_t)b * COUT * HW;
    #pragma unroll
    for (int mi = 0; mi < 4; ++mi)
        #pragma unroll
        for (int nf = 0; nf < 7; ++nf)
            #pragma unroll
            for (int r = 0; r < 4; ++r) {
                const int cout_l = 64 * wv + 16 * mi + 4 * g + r;
                const int p_ = p0 + 16 * nf + ml;
                ob[(size_t)cout_l * HW + p_] = acc[mi][nf][r];
            }
    #undef STAGE_A
    #undef STAGE_X
}

// ---------------- R1 fallback (fp32 sparse direct) ----------------

constexpr int WSZ = CIN * 9;
constexpr int NIN = 54 * 54;

__global__ __launch_bounds__(256)
void sparse_conv3x3(const float* __restrict__ x,
                    const float* __restrict__ wgt,
                    float* __restrict__ out) {
    const int bc = blockIdx.x, cout = bc % COUT, b = bc / COUT;
    const int tid = threadIdx.x;
    __shared__ int2 s_ent[WSZ];
    __shared__ unsigned char s_kk[WSZ];
    __shared__ int s_cnt[257];
    const float* wc = wgt + (size_t)cout * WSZ;
    float mv[9]; int cnt = 0;
    #pragma unroll
    for (int i = 0; i < 9; ++i) { mv[i] = wc[tid * 9 + i]; if (mv[i] != 0.0f) cnt++; }
    s_cnt[tid] = cnt; __syncthreads();
    if (tid == 0) { int run = 0; for (int t = 0; t < 256; ++t) { int c = s_cnt[t]; s_cnt[t] = run; run += c; } s_cnt[256] = run; }
    __syncthreads();
    { int pos = s_cnt[tid];
      #pragma unroll
      for (int i = 0; i < 9; ++i) if (mv[i] != 0.0f) {
          const int kh = i / 3, kw = i - kh * 3;
          int2 e; e.x = (tid * HW + (kh - 1) * W + (kw - 1)) * 4; e.y = __float_as_int(mv[i]);
          s_ent[pos] = e; s_kk[pos] = (unsigned char)(kh | (kw << 4)); pos++; } }
    __syncthreads();
    const int nnz = s_cnt[256];
    const char* xb = (const char*)(x + (size_t)b * CIN * HW);
    float* ob = out + (size_t)bc * HW;
    for (int o = tid; o < HW; o += 256) {
        int h, w; bool interior = (o < NIN);
        if (interior) { h = 1 + o / 54; w = 1 + (o - (h - 1) * 54); }
        else { int o2 = o - NIN;
            if (o2 < 56) { h = 0; w = o2; } else if (o2 < 112) { h = 55; w = o2 - 56; }
            else if (o2 < 166) { h = 1 + (o2 - 112); w = 0; } else { h = 1 + (o2 - 166); w = 55; } }
        const char* pb = xb + (size_t)(h * W + w) * 4;
        float acc = 0.0f;
        if (interior) {
            #pragma unroll 4
            for (int e = 0; e < nnz; ++e) { const int2 en = s_ent[e];
                acc = fmaf(__int_as_float(en.y), *(const float*)(pb + en.x), acc); }
        } else {
            const int h1 = h - 1, w1 = w - 1;
            for (int e = 0; e < nnz; ++e) { const int2 en = s_ent[e]; const int kk = s_kk[e];
                const int hh = h1 + (kk & 15), ww = w1 + (kk >> 4);
                if ((unsigned)hh < (unsigned)H && (unsigned)ww < (unsigned)W)
                    acc = fmaf(__int_as_float(en.y), *(const float*)(pb + en.x), acc); } }
        ob[h * W + w] = acc;
    }
}

// ---------------- launch ----------------

extern "C" void kernel_launch(void* const* d_in, const int* in_sizes, int n_in,
                              void* d_out, int out_size, void* d_ws, size_t ws_size,
                              hipStream_t stream) {
    const float* x = (const float*)d_in[0];
    const float* w = (const float*)d_in[1];
    float* out = (float*)d_out;

    if (ws_size >= WS_NEEDED) {
        ushort* xp = (ushort*)d_ws;
        ushort* wbp = xp + XP_ELEMS;
        prep_xp<<<BB * HP, 256, 0, stream>>>(x, xp);
        prep_wb2<<<(int)(WB_ELEMS / 256), 256, 0, stream>>>(w, wbp);
        conv_mfma<<<896, 256, 0, stream>>>(xp, wbp, out);
    } else {
        sparse_conv3x3<<<BB * COUT, 256, 0, stream>>>(x, w, out);
    }
}

// Round 12
// 153.471 us; speedup vs baseline: 1.3693x; 1.3693x over previous
//
#include <hip/hip_runtime.h>

// 3x3 conv (sparse weights treated dense), NCHW/OIHW, stride1 pad1, fp32 I/O.
// B=32, CIN=COUT=256, H=W=56.
//
// R12 = R10 structure (proven 131.5us) + R11's proven bank-swizzle (proven
// 4x conflict cut), nothing else. Single-variable round.
//  - wave = 64c x 112p m4n7, block 256 thr / 4 waves, acc[4][7] = 112 AGPR.
//  - LDS exact 64B/slot chunks, involution swz(c) = c ^ ((c>>3)&7) applied
//    to gload SOURCE (per-lane, inverse==same) and read addresses.
//  - A 2-deep (16KB each) + X 2-deep (16KB each) = 64KB -> 2 blocks/CU.
//  - per tap: head-wait vmcnt(4|8, never 0 mid-loop) -> barrier -> ds_read
//    4A+7B -> setprio 28 MFMA -> barrier -> tail-stage A(t+2) [+X at tap7].

typedef __attribute__((ext_vector_type(8))) short short8;
typedef __attribute__((ext_vector_type(4))) float f32x4;
typedef __attribute__((ext_vector_type(4))) int i32x4;

constexpr int BB = 32, CIN = 256, COUT = 256, H = 56, W = 56, HW = H * W;
constexpr int HP = 58, WP = 58;

constexpr size_t XP_ELEMS = (size_t)BB * HP * WP * CIN;
constexpr size_t WB_ELEMS = (size_t)COUT * 9 * CIN;
constexpr size_t WS_NEEDED = (XP_ELEMS + WB_ELEMS) * 2;

__device__ __forceinline__ ushort f2bf(float f) {
    unsigned x = __float_as_uint(f);
    unsigned r = (x + 0x7FFFu + ((x >> 16) & 1u)) >> 16;   // RNE
    return (ushort)r;
}

// ---------------- prep kernels (unchanged) ----------------

__global__ __launch_bounds__(256)
void prep_xp(const float* __restrict__ x, ushort* __restrict__ xp) {
    const int bi = blockIdx.x;            // b*58 + padded row i
    const int b = bi / HP, i = bi % HP;
    ushort* dst = xp + (size_t)bi * WP * CIN;
    const int tid = threadIdx.x;

    if (i == 0 || i == HP - 1) {
        i32x4 z = {0, 0, 0, 0};
        for (int k = tid; k < WP * CIN / 8; k += 256) ((i32x4*)dst)[k] = z;
        return;
    }

    __shared__ ushort t[W][CIN + 2];
    const int lane = tid & 63, wv = tid >> 6;
    if (lane < W) {
        const float* src = x + (size_t)b * CIN * HW + (size_t)(i - 1) * W + lane;
        for (int cin = wv; cin < CIN; cin += 4)
            t[lane][cin] = f2bf(src[(size_t)cin * HW]);
    }
    __syncthreads();
    for (int c = 0; c < WP; ++c)
        dst[c * CIN + tid] = (c == 0 || c == WP - 1) ? (ushort)0 : t[c - 1][tid];
}

// wb2: [t = cb*9+tap][cout][ci], ci = cin%32. Slab = 8192 elems.
__global__ __launch_bounds__(256)
void prep_wb2(const float* __restrict__ w, ushort* __restrict__ wb2) {
    const int d = blockIdx.x * 256 + threadIdx.x;
    const int ci = d & 31;
    const int cout = (d >> 5) & 255;
    const int r = d >> 13;                // 0..71
    const int tap = r % 9, cb = r / 9;
    const int cin = cb * 32 + ci;
    wb2[d] = f2bf(w[((size_t)cout * CIN + cin) * 9 + tap]);
}

// ---------------- MFMA conv ----------------

#define SCHED_FENCE() __builtin_amdgcn_sched_barrier(0)
#define WAITV0 asm volatile("s_waitcnt vmcnt(0)" ::: "memory")
#define WAITV4 asm volatile("s_waitcnt vmcnt(4)" ::: "memory")
#define WAITV8 asm volatile("s_waitcnt vmcnt(8)" ::: "memory")

__device__ __forceinline__ void gload_lds16(const ushort* g, ushort* l) {
    __builtin_amdgcn_global_load_lds(
        (const __attribute__((address_space(1))) void*)g,
        (__attribute__((address_space(3))) void*)l, 16, 0, 0);
}

// 16B-chunk involution: mixes bits 3-5 into 0-2; self-inverse.
__device__ __forceinline__ int swz(int c) { return c ^ ((c >> 3) & 7); }

__global__ __launch_bounds__(256, 2)
void conv_mfma(const ushort* __restrict__ xp, const ushort* __restrict__ wb2,
               float* __restrict__ out) {
    // XCD-aware swizzle: 896 blocks = 8 * 112
    int bx = blockIdx.x;
    bx = (bx & 7) * 112 + (bx >> 3);

    const int b  = bx / 28;
    const int p0 = (bx % 28) * 112;        // 112-pix strip = 2 output rows
    const int r0 = p0 / 56;                // first padded input row

    const int tid  = threadIdx.x;
    const int wv   = tid >> 6;             // 0..3, wave -> couts [64wv, 64wv+64)
    const int lane = tid & 63;
    const int ml   = lane & 15;
    const int g    = lane >> 4;

    __shared__ ushort As[2][8192];         // 2 x 16KB, chunk c = cout*4 + piece
    __shared__ ushort Xs[2][8192];         // 2 x 16KB, chunk c = slot*4 + piece
                                           // slot = row*58+col (232 slots, c<928)

    // A-frag read byte offsets (swizzled, constant per thread)
    int aoffB[4];
    #pragma unroll
    for (int mi = 0; mi < 4; ++mi)
        aoffB[mi] = swz((64 * wv + 16 * mi + ml) * 4 + g) * 16;
    // B-frag chunk bases: pixel p_ = p0 + 16nf + ml -> slot*4 + g
    int cbase[7];
    #pragma unroll
    for (int nf = 0; nf < 7; ++nf) {
        const int p_  = p0 + 16 * nf + ml;
        const int hl  = (p_ >= p0 + 56) ? 1 : 0;
        const int col = p_ - 56 * (r0 + hl);
        cbase[nf] = (hl * 58 + col) * 4 + g;
    }
    // staging source offsets: position q = k*256+tid holds logical chunk swz(q)
    int goffA[4], goffX[4];
    #pragma unroll
    for (int k = 0; k < 4; ++k) {
        const int q = k * 256 + tid;
        const int c = swz(q);
        goffA[k] = (c >> 2) * 32 + (c & 3) * 8;                   // slab elems
        goffX[k] = (c < 928) ? ((c >> 2) * 256 + (c & 3) * 8) : 0;
    }
    const size_t xbase = ((size_t)b * HP + r0) * WP * CIN;

    f32x4 acc[4][7] = {};

    #define STAGE_A(SLAB, BUF)                                                  \
        { const ushort* _s = wb2 + (size_t)(SLAB) * 8192;                       \
          _Pragma("unroll")                                                     \
          for (int k = 0; k < 4; ++k)                                           \
              gload_lds16(_s + goffA[k], &As[BUF][(k * 256 + wv * 64) * 8]); }
    #define STAGE_X(CB, BUF)                                                    \
        { const ushort* _s = xp + xbase + (CB) * 32;                            \
          _Pragma("unroll")                                                     \
          for (int k = 0; k < 4; ++k)                                           \
              gload_lds16(_s + goffX[k], &Xs[BUF][(k * 256 + wv * 64) * 8]); }

    // prologue: X(0), A(0), A(1); retire X(0)+A(0), leave A(1) flying
    STAGE_X(0, 0);
    STAGE_A(0, 0);
    STAGE_A(1, 1);
    WAITV4;
    __syncthreads();

    const int DSLOT[9] = {0, 1, 2, 58, 59, 60, 116, 117, 118};

    #pragma unroll
    for (int cb = 0; cb < 8; ++cb) {
        #pragma unroll
        for (int tap = 0; tap < 9; ++tap) {
            const int t = cb * 9 + tap;

            // head: retire A(t) (and X(cb) at tap0, staged before A(t))
            if (tap == 8 && cb < 7) { WAITV8; } else { WAITV4; }
            SCHED_FENCE();
            __builtin_amdgcn_s_barrier();
            SCHED_FENCE();

            // compute
            const ushort* Ab = &As[t & 1][0];
            const ushort* Xb = &Xs[cb & 1][0];

            short8 av[4], bv[7];
            #pragma unroll
            for (int mi = 0; mi < 4; ++mi)
                av[mi] = *(const short8*)((const char*)Ab + aoffB[mi]);
            #pragma unroll
            for (int nf = 0; nf < 7; ++nf) {
                const int c = cbase[nf] + 4 * DSLOT[tap];
                bv[nf] = *(const short8*)((const char*)Xb + swz(c) * 16);
            }

            __builtin_amdgcn_s_setprio(1);
            #pragma unroll
            for (int mi = 0; mi < 4; ++mi)
                #pragma unroll
                for (int nf = 0; nf < 7; ++nf)
                    acc[mi][nf] = __builtin_amdgcn_mfma_f32_16x16x32_bf16(
                                      av[mi], bv[nf], acc[mi][nf], 0, 0, 0);
            __builtin_amdgcn_s_setprio(0);
            SCHED_FENCE();
            __builtin_amdgcn_s_barrier();   // all waves done reading
            SCHED_FENCE();

            // tail: stage into just-freed buffers (A(t+2) -> As[t&1])
            {
                int slab = t + 2;
                if (slab >= 72) slab -= 72; // dummy re-stage, drained at end
                STAGE_A(slab, t & 1);
            }
            if (tap == 7 && cb < 7) STAGE_X(cb + 1, (cb + 1) & 1);
            SCHED_FENCE();
        }
    }
    WAITV0;                                 // drain tail dummy stages

    // epilogue: D[row=4g+r][col=ml] (verified R2-R11)
    float* ob = out + (size_t)b * COUT * HW;
    #pragma unroll
    for (int mi = 0; mi < 4; ++mi)
        #pragma unroll
        for (int nf = 0; nf < 7; ++nf)
            #pragma unroll
            for (int r = 0; r < 4; ++r) {
                const int cout_l = 64 * wv + 16 * mi + 4 * g + r;
                const int p_ = p0 + 16 * nf + ml;
                ob[(size_t)cout_l * HW + p_] = acc[mi][nf][r];
            }
    #undef STAGE_A
    #undef STAGE_X
}

// ---------------- R1 fallback (fp32 sparse direct) ----------------

constexpr int WSZ = CIN * 9;
constexpr int NIN = 54 * 54;

__global__ __launch_bounds__(256)
void sparse_conv3x3(const float* __restrict__ x,
                    const float* __restrict__ wgt,
                    float* __restrict__ out) {
    const int bc = blockIdx.x, cout = bc % COUT, b = bc / COUT;
    const int tid = threadIdx.x;
    __shared__ int2 s_ent[WSZ];
    __shared__ unsigned char s_kk[WSZ];
    __shared__ int s_cnt[257];
    const float* wc = wgt + (size_t)cout * WSZ;
    float mv[9]; int cnt = 0;
    #pragma unroll
    for (int i = 0; i < 9; ++i) { mv[i] = wc[tid * 9 + i]; if (mv[i] != 0.0f) cnt++; }
    s_cnt[tid] = cnt; __syncthreads();
    if (tid == 0) { int run = 0; for (int t = 0; t < 256; ++t) { int c = s_cnt[t]; s_cnt[t] = run; run += c; } s_cnt[256] = run; }
    __syncthreads();
    { int pos = s_cnt[tid];
      #pragma unroll
      for (int i = 0; i < 9; ++i) if (mv[i] != 0.0f) {
          const int kh = i / 3, kw = i - kh * 3;
          int2 e; e.x = (tid * HW + (kh - 1) * W + (kw - 1)) * 4; e.y = __float_as_int(mv[i]);
          s_ent[pos] = e; s_kk[pos] = (unsigned char)(kh | (kw << 4)); pos++; } }
    __syncthreads();
    const int nnz = s_cnt[256];
    const char* xb = (const char*)(x + (size_t)b * CIN * HW);
    float* ob = out + (size_t)bc * HW;
    for (int o = tid; o < HW; o += 256) {
        int h, w; bool interior = (o < NIN);
        if (interior) { h = 1 + o / 54; w = 1 + (o - (h - 1) * 54); }
        else { int o2 = o - NIN;
            if (o2 < 56) { h = 0; w = o2; } else if (o2 < 112) { h = 55; w = o2 - 56; }
            else if (o2 < 166) { h = 1 + (o2 - 112); w = 0; } else { h = 1 + (o2 - 166); w = 55; } }
        const char* pb = xb + (size_t)(h * W + w) * 4;
        float acc = 0.0f;
        if (interior) {
            #pragma unroll 4
            for (int e = 0; e < nnz; ++e) { const int2 en = s_ent[e];
                acc = fmaf(__int_as_float(en.y), *(const float*)(pb + en.x), acc); }
        } else {
            const int h1 = h - 1, w1 = w - 1;
            for (int e = 0; e < nnz; ++e) { const int2 en = s_ent[e]; const int kk = s_kk[e];
                const int hh = h1 + (kk & 15), ww = w1 + (kk >> 4);
                if ((unsigned)hh < (unsigned)H && (unsigned)ww < (unsigned)W)
                    acc = fmaf(__int_as_float(en.y), *(const float*)(pb + en.x), acc); } }
        ob[h * W + w] = acc;
    }
}

// ---------------- launch ----------------

extern "C" void kernel_launch(void* const* d_in, const int* in_sizes, int n_in,
                              void* d_out, int out_size, void* d_ws, size_t ws_size,
                              hipStream_t stream) {
    const float* x = (const float*)d_in[0];
    const float* w = (const float*)d_in[1];
    float* out = (float*)d_out;

    if (ws_size >= WS_NEEDED) {
        ushort* xp = (ushort*)d_ws;
        ushort* wbp = xp + XP_ELEMS;
        prep_xp<<<BB * HP, 256, 0, stream>>>(x, xp);
        prep_wb2<<<(int)(WB_ELEMS / 256), 256, 0, stream>>>(w, wbp);
        conv_mfma<<<896, 256, 0, stream>>>(xp, wbp, out);
    } else {
        sparse_conv3x3<<<BB * COUT, 256, 0, stream>>>(x, w, out);
    }
}